// Round 12
// baseline (2079.166 us; speedup 1.0000x reference)
//
#include <hip/hip_runtime.h>
#include <hip/hip_bf16.h>

typedef __attribute__((ext_vector_type(4))) float f32x4;
typedef __attribute__((ext_vector_type(16))) float f32x16;
typedef __attribute__((ext_vector_type(8))) _Float16 f16x8;

static __device__ __forceinline__ unsigned short h2u(_Float16 h) {
  union { _Float16 h; unsigned short u; } v; v.h = h; return v.u;
}

#define MFMA16(a, b, c) __builtin_amdgcn_mfma_f32_16x16x32_f16(a, b, c, 0, 0, 0)
#define MFMA32(a, b, c) __builtin_amdgcn_mfma_f32_32x32x16_f16(a, b, c, 0, 0, 0)

// ---------------- init kernels ----------------

// gate-interleaved Wg: out row n' = u*4+gate <- [W_ih|W_hh] row gate*128+u
__global__ void build_wg(const float* __restrict__ W_ih, const float* __restrict__ W_hh,
                         _Float16* __restrict__ Wg) {
  int i = blockIdx.x * 256 + threadIdx.x;
  if (i < 512 * 192) {
    int rp = i / 192, k = i % 192;
    int u = rp >> 2, gate = rp & 3;
    int sr = gate * 128 + u;
    float v = (k < 64) ? W_ih[sr * 64 + k] : W_hh[sr * 128 + (k - 64)];
    _Float16 h = (_Float16)v;
    Wg[i] = h;
    Wg[512 * 192 + i] = (_Float16)(v - (float)h);
  }
}

__global__ void build_wp1b(const float* __restrict__ Wp1, _Float16* __restrict__ W) {
  int i = blockIdx.x * 256 + threadIdx.x;
  if (i < 512 * 128) {
    int r = i >> 7, k = i & 127;
    float v = Wp1[r * 192 + 64 + k];
    _Float16 h = (_Float16)v;
    W[i] = h;
    W[512 * 128 + i] = (_Float16)(v - (float)h);
  }
}

// f32 [N,K] row-major -> 16-col frag-ordered split-f16 (for gemm_f16f)
__global__ void refrag_f32(const float* __restrict__ W, _Float16* __restrict__ F,
                           int N, int Kc) {
  int idx = blockIdx.x * 256 + threadIdx.x;
  int total = (N >> 4) * Kc * 64;
  if (idx >= total) return;
  int l = idx & 63;
  int c = (idx >> 6) % Kc;
  int T = (idx >> 6) / Kc;
  int n = T * 16 + (l & 15);
  int k = c * 32 + (l >> 4) * 8;
  int K = Kc * 32;
  const float* src = W + (size_t)n * K + k;
  _Float16* dst = F + ((size_t)((T * Kc + c) * 2) * 64 + l) * 8;
  for (int e = 0; e < 8; e++) {
    float v = src[e];
    _Float16 h = (_Float16)v;
    dst[e] = h;
    dst[512 + e] = (_Float16)(v - (float)h);
  }
}

// split-plane [N,K] -> 16-col frag-ordered
__global__ void refrag_planes(const _Float16* __restrict__ Ws, size_t plane,
                              _Float16* __restrict__ F, int N, int Kc) {
  int idx = blockIdx.x * 256 + threadIdx.x;
  int total = (N >> 4) * Kc * 64;
  if (idx >= total) return;
  int l = idx & 63;
  int c = (idx >> 6) % Kc;
  int T = (idx >> 6) / Kc;
  int n = T * 16 + (l & 15);
  int k = c * 32 + (l >> 4) * 8;
  int K = Kc * 32;
  const _Float16* src = Ws + (size_t)n * K + k;
  _Float16* dst = F + ((size_t)((T * Kc + c) * 2) * 64 + l) * 8;
  for (int e = 0; e < 8; e++) {
    dst[e] = src[e];
    dst[512 + e] = src[plane + e];
  }
}

// Wp2 [1024,512] f32 -> 32-col frag order for mfma_32x32x16:
// frag (T32, c16, kh, plane): elem n = T32*32+(l&31), k = c16*32+kh*16+(l>>5)*8+e
// dst f16 offset = (((T32*16 + c16)*4 + kh*2 + plane)*64 + l)*8
__global__ void build_w2f32(const float* __restrict__ Wp2, _Float16* __restrict__ F) {
  int idx = blockIdx.x * 256 + threadIdx.x;  // 32*16*2*64 = 65536
  if (idx >= 65536) return;
  int l = idx & 63;
  int kh = (idx >> 6) & 1;
  int c = (idx >> 7) & 15;
  int T = idx >> 11;
  int n = T * 32 + (l & 31);
  int kbase = c * 32 + kh * 16 + (l >> 5) * 8;
  _Float16* dst = F + ((size_t)((T * 16 + c) * 4 + kh * 2) * 64 + l) * 8;
  for (int e = 0; e < 8; e++) {
    float v = Wp2[(size_t)n * 512 + kbase + e];
    _Float16 h = (_Float16)v;
    dst[e] = h;
    dst[512 + e] = (_Float16)(v - (float)h);
  }
}

__global__ void build_misc(const float* __restrict__ Wp1, const float* __restrict__ Wp_emb,
                           const float* __restrict__ bp_emb, const float* __restrict__ bp1,
                           const float* __restrict__ b_ih, const float* __restrict__ b_hh,
                           float* __restrict__ Uc, float* __restrict__ c1,
                           float* __restrict__ bias_gi) {
  int r = blockIdx.x * 256 + threadIdx.x;
  if (r < 512) {
    float u0 = 0.f, u1 = 0.f, cc = 0.f;
    for (int e = 0; e < 64; e++) {
      float w = Wp1[r * 192 + e];
      u0 += w * Wp_emb[e * 2 + 0];
      u1 += w * Wp_emb[e * 2 + 1];
      cc += w * bp_emb[e];
    }
    Uc[r * 2 + 0] = u0;
    Uc[r * 2 + 1] = u1;
    c1[r] = bp1[r] + cc;
    int u = r >> 2, gate = r & 3;
    bias_gi[r] = b_ih[gate * 128 + u] + b_hh[gate * 128 + u];
  }
}

__global__ void init_state(const float* __restrict__ lp, const float* __restrict__ lpr,
                           const float* __restrict__ h0, const float* __restrict__ c0,
                           const float* __restrict__ W_emb, const float* __restrict__ b_emb,
                           _Float16* __restrict__ A_lstm, size_t PL_AL,
                           float* __restrict__ c_state, float* __restrict__ curr_pos) {
  int row = blockIdx.x;
  int t = threadIdx.x;  // 192
  float v;
  if (t < 64) {
    v = lpr[row * 2] * W_emb[t * 2] + lpr[row * 2 + 1] * W_emb[t * 2 + 1] + b_emb[t];
  } else {
    int u = t - 64;
    v = h0[(size_t)row * 128 + u];
    c_state[(size_t)row * 128 + u] = c0[(size_t)row * 128 + u];
  }
  _Float16 h = (_Float16)v;
  A_lstm[(size_t)row * 192 + t] = h;
  A_lstm[PL_AL + (size_t)row * 192 + t] = (_Float16)(v - (float)h);
  if (t < 2) curr_pos[row * 2 + t] = lp[row * 2 + t];
}

// ---------------- generic split-fp16 GEMM (proven): LDS A + frag-B ----------

template <int K, int RELU>
__global__ __launch_bounds__(256) void gemm_f16f(
    const _Float16* __restrict__ A, size_t aPl, int lda,
    const _Float16* __restrict__ Bf,
    const float* __restrict__ bias,
    float* __restrict__ outF, int ldoF,
    _Float16* __restrict__ outS, size_t oPl, int ldoS) {
  constexpr int Kc = K / 32;
  __shared__ _Float16 Ah[64][40], Al[64][40];
  const int tid = threadIdx.x;
  const int lane = tid & 63;
  const int wid = tid >> 6;
  const int wm = wid & 1, wn = wid >> 1;
  const int m0 = blockIdx.x * 64, n0 = blockIdx.y * 64;

  f32x4 acc[2][2];
#pragma unroll
  for (int a = 0; a < 2; a++)
#pragma unroll
    for (int b = 0; b < 2; b++) acc[a][b] = (f32x4){0.f, 0.f, 0.f, 0.f};

  const int srow = tid >> 2, sc = (tid & 3) * 8;
  const int ar = wm * 32 + (lane & 15);
  const int kk = (lane >> 4) * 8;
  const int T0 = (n0 >> 4) + wn * 2;

  for (int c = 0; c < Kc; c++) {
    const int k0 = c * 32;
    const _Float16* ap = A + (size_t)(m0 + srow) * lda + k0 + sc;
    uint4 avh = *(const uint4*)ap;
    uint4 avl = *(const uint4*)(ap + aPl);
    const _Float16* fb0 = Bf + ((size_t)((T0 * Kc + c) * 2) * 64 + lane) * 8;
    const _Float16* fb1 = Bf + ((size_t)(((T0 + 1) * Kc + c) * 2) * 64 + lane) * 8;
    f16x8 bh0 = *(const f16x8*)fb0, bl0 = *(const f16x8*)(fb0 + 512);
    f16x8 bh1 = *(const f16x8*)fb1, bl1 = *(const f16x8*)(fb1 + 512);
    *(uint4*)&Ah[srow][sc] = avh;
    *(uint4*)&Al[srow][sc] = avl;
    __syncthreads();
    f16x8 ah0 = *(const f16x8*)&Ah[ar][kk];
    f16x8 ah1 = *(const f16x8*)&Ah[ar + 16][kk];
    f16x8 al0 = *(const f16x8*)&Al[ar][kk];
    f16x8 al1 = *(const f16x8*)&Al[ar + 16][kk];
    acc[0][0] = MFMA16(ah0, bh0, acc[0][0]);
    acc[0][0] = MFMA16(ah0, bl0, acc[0][0]);
    acc[0][0] = MFMA16(al0, bh0, acc[0][0]);
    acc[0][1] = MFMA16(ah0, bh1, acc[0][1]);
    acc[0][1] = MFMA16(ah0, bl1, acc[0][1]);
    acc[0][1] = MFMA16(al0, bh1, acc[0][1]);
    acc[1][0] = MFMA16(ah1, bh0, acc[1][0]);
    acc[1][0] = MFMA16(ah1, bl0, acc[1][0]);
    acc[1][0] = MFMA16(al1, bh0, acc[1][0]);
    acc[1][1] = MFMA16(ah1, bh1, acc[1][1]);
    acc[1][1] = MFMA16(ah1, bl1, acc[1][1]);
    acc[1][1] = MFMA16(al1, bh1, acc[1][1]);
    __syncthreads();
  }
#pragma unroll
  for (int mi = 0; mi < 2; mi++)
#pragma unroll
    for (int ni = 0; ni < 2; ni++)
#pragma unroll
      for (int r = 0; r < 4; r++) {
        int row = m0 + wm * 32 + mi * 16 + (lane >> 4) * 4 + r;
        int col = n0 + wn * 32 + ni * 16 + (lane & 15);
        float v = acc[mi][ni][r];
        if (bias) v += bias[col];
        if (RELU) v = fmaxf(v, 0.f);
        if (outF) outF[(size_t)row * ldoF + col] = v;
        if (outS) {
          _Float16 h = (_Float16)v;
          outS[(size_t)row * ldoS + col] = h;
          outS[oPl + (size_t)row * ldoS + col] = (_Float16)(v - (float)h);
        }
      }
}

// ---------------- fused gates GEMM + LSTM pointwise ----------------

__global__ __launch_bounds__(256) void gates_lstm(
    const _Float16* __restrict__ A, size_t aPl,
    const _Float16* __restrict__ Bf,
    const float* __restrict__ bias,
    float* __restrict__ c_state,
    _Float16* __restrict__ A_mlp, size_t oPl) {
  constexpr int Kc = 6;
  __shared__ _Float16 Ah[64][40], Al[64][40];
  __shared__ float sacc[64][68];
  const int tid = threadIdx.x;
  const int lane = tid & 63;
  const int wid = tid >> 6;
  const int wm = wid & 1, wn = wid >> 1;
  const int m0 = blockIdx.x * 64, n0 = blockIdx.y * 64;

  f32x4 acc[2][2];
#pragma unroll
  for (int a = 0; a < 2; a++)
#pragma unroll
    for (int b = 0; b < 2; b++) acc[a][b] = (f32x4){0.f, 0.f, 0.f, 0.f};

  const int srow = tid >> 2, sc = (tid & 3) * 8;
  const int ar = wm * 32 + (lane & 15);
  const int kk = (lane >> 4) * 8;
  const int T0 = (n0 >> 4) + wn * 2;

  for (int c = 0; c < Kc; c++) {
    const int k0 = c * 32;
    const _Float16* ap = A + (size_t)(m0 + srow) * 192 + k0 + sc;
    uint4 avh = *(const uint4*)ap;
    uint4 avl = *(const uint4*)(ap + aPl);
    const _Float16* fb0 = Bf + ((size_t)((T0 * Kc + c) * 2) * 64 + lane) * 8;
    const _Float16* fb1 = Bf + ((size_t)(((T0 + 1) * Kc + c) * 2) * 64 + lane) * 8;
    f16x8 bh0 = *(const f16x8*)fb0, bl0 = *(const f16x8*)(fb0 + 512);
    f16x8 bh1 = *(const f16x8*)fb1, bl1 = *(const f16x8*)(fb1 + 512);
    *(uint4*)&Ah[srow][sc] = avh;
    *(uint4*)&Al[srow][sc] = avl;
    __syncthreads();
    f16x8 ah0 = *(const f16x8*)&Ah[ar][kk];
    f16x8 ah1 = *(const f16x8*)&Ah[ar + 16][kk];
    f16x8 al0 = *(const f16x8*)&Al[ar][kk];
    f16x8 al1 = *(const f16x8*)&Al[ar + 16][kk];
    acc[0][0] = MFMA16(ah0, bh0, acc[0][0]);
    acc[0][0] = MFMA16(ah0, bl0, acc[0][0]);
    acc[0][0] = MFMA16(al0, bh0, acc[0][0]);
    acc[0][1] = MFMA16(ah0, bh1, acc[0][1]);
    acc[0][1] = MFMA16(ah0, bl1, acc[0][1]);
    acc[0][1] = MFMA16(al0, bh1, acc[0][1]);
    acc[1][0] = MFMA16(ah1, bh0, acc[1][0]);
    acc[1][0] = MFMA16(ah1, bl0, acc[1][0]);
    acc[1][0] = MFMA16(al1, bh0, acc[1][0]);
    acc[1][1] = MFMA16(ah1, bh1, acc[1][1]);
    acc[1][1] = MFMA16(ah1, bl1, acc[1][1]);
    acc[1][1] = MFMA16(al1, bh1, acc[1][1]);
    __syncthreads();
  }
#pragma unroll
  for (int mi = 0; mi < 2; mi++)
#pragma unroll
    for (int ni = 0; ni < 2; ni++)
#pragma unroll
      for (int r = 0; r < 4; r++) {
        int row_l = wm * 32 + mi * 16 + (lane >> 4) * 4 + r;
        int col_l = wn * 32 + ni * 16 + (lane & 15);
        sacc[row_l][col_l] = acc[mi][ni][r] + bias[n0 + col_l];
      }
  __syncthreads();
  const int n0u = n0 >> 2;
#pragma unroll
  for (int q = 0; q < 4; q++) {
    int cell = q * 256 + tid;
    int r_l = cell >> 4, u_l = cell & 15;
    float gi = sacc[r_l][u_l * 4 + 0];
    float gf = sacc[r_l][u_l * 4 + 1];
    float gg = sacc[r_l][u_l * 4 + 2];
    float go = sacc[r_l][u_l * 4 + 3];
    int row = m0 + r_l, u = n0u + u_l;
    float si = 1.f / (1.f + expf(-gi));
    float sf = 1.f / (1.f + expf(-gf));
    float so = 1.f / (1.f + expf(-go));
    float cst = sf * c_state[(size_t)row * 128 + u] + si * tanhf(gg);
    c_state[(size_t)row * 128 + u] = cst;
    float h = so * tanhf(cst);
    _Float16 hh = (_Float16)h;
    A_mlp[(size_t)row * 1152 + u] = hh;
    A_mlp[oPl + (size_t)row * 1152 + u] = (_Float16)(h - (float)hh);
  }
}

// ---------------- hpart GEMM + fused pose head / dec_in (by==0) ----------------

__global__ __launch_bounds__(256) void hpart_pose(
    const _Float16* __restrict__ A, size_t aPl,
    const _Float16* __restrict__ Bf,
    const float* __restrict__ c1,
    float* __restrict__ hpart,
    const float* __restrict__ W_pos, const float* __restrict__ b_pos,
    const float* __restrict__ W_emb, const float* __restrict__ b_emb,
    float* __restrict__ rels_out, float* __restrict__ curr_pos,
    _Float16* __restrict__ A_lstm, size_t alPl) {
  constexpr int Kc = 4;
  __shared__ _Float16 Ah[64][40], Al[64][40];
  __shared__ float srel[64][2];
  const int tid = threadIdx.x;
  const int lane = tid & 63;
  const int wid = tid >> 6;
  const int wm = wid & 1, wn = wid >> 1;
  const int m0 = blockIdx.x * 64, n0 = blockIdx.y * 64;
  const int by0 = (blockIdx.y == 0);

  f32x4 acc[2][2];
#pragma unroll
  for (int a = 0; a < 2; a++)
#pragma unroll
    for (int b = 0; b < 2; b++) acc[a][b] = (f32x4){0.f, 0.f, 0.f, 0.f};

  const int srow = tid >> 2, sc = (tid & 3) * 8;
  const int ar = wm * 32 + (lane & 15);
  const int kk = (lane >> 4) * 8;
  const int T0 = (n0 >> 4) + wn * 2;
  float pp0 = 0.f, pp1 = 0.f;

  for (int c = 0; c < Kc; c++) {
    const int k0 = c * 32;
    const _Float16* ap = A + (size_t)(m0 + srow) * 1152 + k0 + sc;
    uint4 avh = *(const uint4*)ap;
    uint4 avl = *(const uint4*)(ap + aPl);
    if (by0) {
      union { uint4 u; _Float16 f[8]; } uh, ul;
      uh.u = avh; ul.u = avl;
#pragma unroll
      for (int e = 0; e < 8; e++) {
        float hv = (float)uh.f[e] + (float)ul.f[e];
        int k = k0 + sc + e;
        pp0 += hv * W_pos[k];
        pp1 += hv * W_pos[128 + k];
      }
    }
    const _Float16* fb0 = Bf + ((size_t)((T0 * Kc + c) * 2) * 64 + lane) * 8;
    const _Float16* fb1 = Bf + ((size_t)(((T0 + 1) * Kc + c) * 2) * 64 + lane) * 8;
    f16x8 bh0 = *(const f16x8*)fb0, bl0 = *(const f16x8*)(fb0 + 512);
    f16x8 bh1 = *(const f16x8*)fb1, bl1 = *(const f16x8*)(fb1 + 512);
    *(uint4*)&Ah[srow][sc] = avh;
    *(uint4*)&Al[srow][sc] = avl;
    __syncthreads();
    f16x8 ah0 = *(const f16x8*)&Ah[ar][kk];
    f16x8 ah1 = *(const f16x8*)&Ah[ar + 16][kk];
    f16x8 al0 = *(const f16x8*)&Al[ar][kk];
    f16x8 al1 = *(const f16x8*)&Al[ar + 16][kk];
    acc[0][0] = MFMA16(ah0, bh0, acc[0][0]);
    acc[0][0] = MFMA16(ah0, bl0, acc[0][0]);
    acc[0][0] = MFMA16(al0, bh0, acc[0][0]);
    acc[0][1] = MFMA16(ah0, bh1, acc[0][1]);
    acc[0][1] = MFMA16(ah0, bl1, acc[0][1]);
    acc[0][1] = MFMA16(al0, bh1, acc[0][1]);
    acc[1][0] = MFMA16(ah1, bh0, acc[1][0]);
    acc[1][0] = MFMA16(ah1, bl0, acc[1][0]);
    acc[1][0] = MFMA16(al1, bh0, acc[1][0]);
    acc[1][1] = MFMA16(ah1, bh1, acc[1][1]);
    acc[1][1] = MFMA16(ah1, bl1, acc[1][1]);
    acc[1][1] = MFMA16(al1, bh1, acc[1][1]);
    __syncthreads();
  }
#pragma unroll
  for (int mi = 0; mi < 2; mi++)
#pragma unroll
    for (int ni = 0; ni < 2; ni++)
#pragma unroll
      for (int r = 0; r < 4; r++) {
        int row = m0 + wm * 32 + mi * 16 + (lane >> 4) * 4 + r;
        int col = n0 + wn * 32 + ni * 16 + (lane & 15);
        hpart[(size_t)row * 512 + col] = acc[mi][ni][r] + c1[col];
      }
  if (by0) {
    pp0 += __shfl_xor(pp0, 1);
    pp0 += __shfl_xor(pp0, 2);
    pp1 += __shfl_xor(pp1, 1);
    pp1 += __shfl_xor(pp1, 2);
    if ((tid & 3) == 0) {
      int row = m0 + srow;
      float r0 = pp0 + b_pos[0], r1 = pp1 + b_pos[1];
      rels_out[(size_t)row * 2 + 0] = r0;
      rels_out[(size_t)row * 2 + 1] = r1;
      curr_pos[(size_t)row * 2 + 0] += r0;
      curr_pos[(size_t)row * 2 + 1] += r1;
      srel[srow][0] = r0;
      srel[srow][1] = r1;
    }
    __syncthreads();
#pragma unroll
    for (int q = 0; q < 16; q++) {
      int idx = q * 256 + tid;
      int r_l = idx >> 6, cc = idx & 63;
      int row = m0 + r_l;
      float v = srel[r_l][0] * W_emb[cc * 2] + srel[r_l][1] * W_emb[cc * 2 + 1] + b_emb[cc];
      _Float16 hh = (_Float16)v;
      A_lstm[(size_t)row * 192 + cc] = hh;
      A_lstm[alPl + (size_t)row * 192 + cc] = (_Float16)(v - (float)hh);
    }
  }
}

// ---------------- fused pool: R4 structure, 32x32x16 MFMA (1 col-tile/wave) ----
// grid: 64 g x 6 it x 4 nt = 1536 blocks; tile 96 rows x 256 cols, K=512 (16 steps).
// waves 1x8: wave w owns cols w*32..+32 of the 256-col quarter; acc = 3 x f32x16 (48 AGPR).

__global__ __launch_bounds__(512) void pool_gemm(
    const float* __restrict__ hpart,
    const float* __restrict__ curr_pos,
    const float* __restrict__ Uc,
    const _Float16* __restrict__ W2f,    // 32-col frag-ordered (build_w2f32)
    const float* __restrict__ bp2,
    _Float16* __restrict__ A_mlp, size_t oPl) {
  __shared__ _Float16 Ah[96][40], Al[96][40];
  __shared__ float Us0[96], Us1[96];
  __shared__ int pool_tile[4][256];
  int b = blockIdx.x;
  int nt = b & 3;
  int it = (b >> 2) % 6;
  int g = b / 24;
  int tid = threadIdx.x;
  int lane = tid & 63, wid = tid >> 6;   // wid = wave col-tile within quarter

  int* pt = &pool_tile[0][0];
  pt[tid] = 0;
  pt[tid + 512] = 0;

  if (tid < 96) {
    int r = tid;
    int i = it * 4 + r / 24;
    int j = r % 24;
    float pix = curr_pos[(g * 24 + i) * 2 + 0];
    float piy = curr_pos[(g * 24 + i) * 2 + 1];
    float dx = curr_pos[(g * 24 + j) * 2 + 0] - pix;
    float dy = curr_pos[(g * 24 + j) * 2 + 1] - piy;
    float nrm = sqrtf(dx * dx + dy * dy);
    float inv = 1.f / fmaxf(nrm, 1e-12f);
    Us0[r] = dx * inv;
    Us1[r] = dy * inv;
  }

  f32x16 acc[3];
#pragma unroll
  for (int a = 0; a < 3; a++)
#pragma unroll
    for (int q = 0; q < 16; q++) acc[a][q] = 0.f;

  const int kc = (2 * tid) & 31;
  const int rb = tid >> 4;
  const int l31 = lane & 31;
  const int kh8 = (lane >> 5) * 8;
  const int T32 = nt * 8 + wid;

  for (int c16 = 0; c16 < 16; c16++) {
    const int k0 = c16 * 32;
    // B fragments for this K-step: kh0 hi/lo, kh1 hi/lo (1KB/wave each, coalesced)
    const _Float16* fb = W2f + (size_t)((T32 * 16 + c16) * 4) * 512 + lane * 8;
    f16x8 b0h = *(const f16x8*)(fb);
    f16x8 b0l = *(const f16x8*)(fb + 512);
    f16x8 b1h = *(const f16x8*)(fb + 1024);
    f16x8 b1l = *(const f16x8*)(fb + 1536);
    __syncthreads();  // A buffers free (prev reads done); Us ready on first iter
    // build A slice [96][32]
#pragma unroll
    for (int s = 0; s < 3; s++) {
      int r = s * 32 + rb;
      int j = r % 24;
      float2 hp = *(const float2*)(hpart + ((size_t)(g * 24 + j)) * 512 + k0 + kc);
      float4 uc = *(const float4*)(Uc + (size_t)(k0 + kc) * 2);
      float u0 = Us0[r], u1 = Us1[r];
      float v0 = fmaxf(hp.x + u0 * uc.x + u1 * uc.y, 0.f);
      float v1 = fmaxf(hp.y + u0 * uc.z + u1 * uc.w, 0.f);
      _Float16 h0v = (_Float16)v0, h1v = (_Float16)v1;
      _Float16 l0v = (_Float16)(v0 - (float)h0v), l1v = (_Float16)(v1 - (float)h1v);
      *(unsigned int*)&Ah[r][kc] = (unsigned int)h2u(h0v) | ((unsigned int)h2u(h1v) << 16);
      *(unsigned int*)&Al[r][kc] = (unsigned int)h2u(l0v) | ((unsigned int)h2u(l1v) << 16);
    }
    __syncthreads();
    // kh = 0 (k 0..15 of the 32-slice)
#pragma unroll
    for (int rt = 0; rt < 3; rt++) {
      f16x8 a0h = *(const f16x8*)&Ah[rt * 32 + l31][kh8];
      f16x8 a0l = *(const f16x8*)&Al[rt * 32 + l31][kh8];
      acc[rt] = MFMA32(a0h, b0h, acc[rt]);
      acc[rt] = MFMA32(a0h, b0l, acc[rt]);
      acc[rt] = MFMA32(a0l, b0h, acc[rt]);
    }
    // kh = 1 (k 16..31)
#pragma unroll
    for (int rt = 0; rt < 3; rt++) {
      f16x8 a1h = *(const f16x8*)&Ah[rt * 32 + l31][16 + kh8];
      f16x8 a1l = *(const f16x8*)&Al[rt * 32 + l31][16 + kh8];
      acc[rt] = MFMA32(a1h, b1h, acc[rt]);
      acc[rt] = MFMA32(a1h, b1l, acc[rt]);
      acc[rt] = MFMA32(a1l, b1h, acc[rt]);
    }
  }
  __syncthreads();
  // epilogue: C/D 32x32 layout col=lane&31, row=(reg&3)+8*(reg>>2)+4*(lane>>5)
  const int nl = wid * 32 + l31;
  const float bb = bp2[nt * 256 + nl];
#pragma unroll
  for (int rt = 0; rt < 3; rt++)
#pragma unroll
    for (int reg = 0; reg < 16; reg++) {
      int rl = rt * 32 + (reg & 3) + 8 * (reg >> 2) + 4 * (lane >> 5);
      int il = rl / 24;
      float z = fmaxf(acc[rt][reg] + bb, 0.f);
      atomicMax(&pool_tile[il][nl], __float_as_int(z));
    }
  __syncthreads();
  for (int idx = tid; idx < 1024; idx += 512) {
    int il = idx >> 8, nl2 = idx & 255;
    int row = g * 24 + it * 4 + il;
    float z = __int_as_float(pool_tile[il][nl2]);
    _Float16 h = (_Float16)z;
    A_mlp[(size_t)row * 1152 + 128 + nt * 256 + nl2] = h;
    A_mlp[oPl + (size_t)row * 1152 + 128 + nt * 256 + nl2] = (_Float16)(z - (float)h);
  }
}

// ---------------- host ----------------

extern "C" void kernel_launch(void* const* d_in, const int* in_sizes, int n_in,
                              void* d_out, int out_size, void* d_ws, size_t ws_size,
                              hipStream_t stream) {
  (void)in_sizes; (void)n_in; (void)out_size; (void)ws_size;
  const float* last_pos     = (const float*)d_in[0];
  const float* last_pos_rel = (const float*)d_in[1];
  const float* h0    = (const float*)d_in[2];
  const float* c0    = (const float*)d_in[3];
  const float* W_emb = (const float*)d_in[5];
  const float* b_emb = (const float*)d_in[6];
  const float* W_ih  = (const float*)d_in[7];
  const float* W_hh  = (const float*)d_in[8];
  const float* b_ih  = (const float*)d_in[9];
  const float* b_hh  = (const float*)d_in[10];
  const float* W_pos = (const float*)d_in[11];
  const float* b_pos = (const float*)d_in[12];
  const float* Wp_emb = (const float*)d_in[13];
  const float* bp_emb = (const float*)d_in[14];
  const float* Wp1 = (const float*)d_in[15];
  const float* bp1 = (const float*)d_in[16];
  const float* Wp2 = (const float*)d_in[17];
  const float* bp2 = (const float*)d_in[18];
  const float* Wm1 = (const float*)d_in[19];
  const float* bm1 = (const float*)d_in[20];
  const float* Wm2 = (const float*)d_in[21];
  const float* bm2 = (const float*)d_in[22];

  const size_t PL_AL = (size_t)1536 * 192;
  const size_t PL_AM = (size_t)1536 * 1152;
  const size_t PL_DH = (size_t)1536 * 1024;

  char* ws = (char*)d_ws;
  size_t off = 0;
  auto alloc = [&](size_t bytes) -> void* {
    void* p = ws + off;
    off = (off + bytes + 255) & ~(size_t)255;
    return p;
  };
  _Float16* Wgi_s  = (_Float16*)alloc((size_t)512 * 192 * 2 * 2);
  _Float16* Wp1b_s = (_Float16*)alloc((size_t)512 * 128 * 2 * 2);
  _Float16* Wgi_f  = (_Float16*)alloc((size_t)32 * 6 * 1024 * 2);
  _Float16* Wp1b_f = (_Float16*)alloc((size_t)32 * 4 * 1024 * 2);
  _Float16* W2f    = (_Float16*)alloc((size_t)32 * 16 * 4 * 512 * 2);  // 32-col frag order
  _Float16* Wm1_f  = (_Float16*)alloc((size_t)64 * 36 * 1024 * 2);
  _Float16* Wm2_f  = (_Float16*)alloc((size_t)8 * 32 * 1024 * 2);
  float* Uc      = (float*)alloc(512 * 2 * 4);
  float* c1      = (float*)alloc(512 * 4);
  float* bias_gi = (float*)alloc(512 * 4);
  _Float16* A_lstm = (_Float16*)alloc(PL_AL * 2 * 2);
  float* c_state = (float*)alloc((size_t)1536 * 128 * 4);
  _Float16* A_mlp = (_Float16*)alloc(PL_AM * 2 * 2);
  float* curr_pos = (float*)alloc(1536 * 2 * 4);
  float* hpart = (float*)alloc((size_t)1536 * 512 * 4);
  _Float16* dh = (_Float16*)alloc(PL_DH * 2 * 2);

  float* rels = (float*)d_out;                      // [12,1536,2]
  float* h_out = ((float*)d_out) + 12 * 1536 * 2;   // [1536,128]

  // ---- init weights + state ----
  build_wg<<<(98304 + 255) / 256, 256, 0, stream>>>(W_ih, W_hh, Wgi_s);
  build_wp1b<<<(65536 + 255) / 256, 256, 0, stream>>>(Wp1, Wp1b_s);
  refrag_planes<<<(12288 + 255) / 256, 256, 0, stream>>>(Wgi_s, 98304, Wgi_f, 512, 6);
  refrag_planes<<<(8192 + 255) / 256, 256, 0, stream>>>(Wp1b_s, 65536, Wp1b_f, 512, 4);
  build_w2f32<<<256, 256, 0, stream>>>(Wp2, W2f);
  refrag_f32<<<(147456 + 255) / 256, 256, 0, stream>>>(Wm1, Wm1_f, 1024, 36);
  refrag_f32<<<(16384 + 255) / 256, 256, 0, stream>>>(Wm2, Wm2_f, 128, 32);
  build_misc<<<2, 256, 0, stream>>>(Wp1, Wp_emb, bp_emb, bp1, b_ih, b_hh, Uc, c1, bias_gi);
  init_state<<<1536, 192, 0, stream>>>(last_pos, last_pos_rel, h0, c0, W_emb, b_emb,
                                       A_lstm, PL_AL, c_state, curr_pos);

  for (int t = 0; t < 12; t++) {
    gates_lstm<<<dim3(24, 8), 256, 0, stream>>>(A_lstm, PL_AL, Wgi_f, bias_gi,
                                                c_state, A_mlp, PL_AM);
    hpart_pose<<<dim3(24, 8), 256, 0, stream>>>(A_mlp, PL_AM, Wp1b_f, c1, hpart,
                                                W_pos, b_pos, W_emb, b_emb,
                                                rels + (size_t)t * 1536 * 2, curr_pos,
                                                A_lstm, PL_AL);
    pool_gemm<<<1536, 512, 0, stream>>>(hpart, curr_pos, Uc, W2f, bp2, A_mlp, PL_AM);
    gemm_f16f<1152, 1><<<dim3(24, 16), 256, 0, stream>>>(
        A_mlp, PL_AM, 1152, Wm1_f, bm1, (float*)nullptr, 0, dh, PL_DH, 1024);
    float* houtF = (t == 11) ? h_out : (float*)nullptr;
    gemm_f16f<1024, 1><<<dim3(24, 2), 256, 0, stream>>>(
        dh, PL_DH, 1024, Wm2_f, bm2, houtF, 128, A_lstm + 64, PL_AL, 192);
  }
}

// Round 13
// 1805.721 us; speedup vs baseline: 1.1514x; 1.1514x over previous
//
#include <hip/hip_runtime.h>
#include <hip/hip_bf16.h>

typedef __attribute__((ext_vector_type(4))) float f32x4;
typedef __attribute__((ext_vector_type(8))) _Float16 f16x8;

static __device__ __forceinline__ unsigned short h2u(_Float16 h) {
  union { _Float16 h; unsigned short u; } v; v.h = h; return v.u;
}

#define MFMA16(a, b, c) __builtin_amdgcn_mfma_f32_16x16x32_f16(a, b, c, 0, 0, 0)

// ---------------- init kernels ----------------

// gate-interleaved Wg: out row n' = u*4+gate <- [W_ih|W_hh] row gate*128+u
__global__ void build_wg(const float* __restrict__ W_ih, const float* __restrict__ W_hh,
                         _Float16* __restrict__ Wg) {
  int i = blockIdx.x * 256 + threadIdx.x;
  if (i < 512 * 192) {
    int rp = i / 192, k = i % 192;
    int u = rp >> 2, gate = rp & 3;
    int sr = gate * 128 + u;
    float v = (k < 64) ? W_ih[sr * 64 + k] : W_hh[sr * 128 + (k - 64)];
    _Float16 h = (_Float16)v;
    Wg[i] = h;
    Wg[512 * 192 + i] = (_Float16)(v - (float)h);
  }
}

__global__ void build_wp1b(const float* __restrict__ Wp1, _Float16* __restrict__ W) {
  int i = blockIdx.x * 256 + threadIdx.x;
  if (i < 512 * 128) {
    int r = i >> 7, k = i & 127;
    float v = Wp1[r * 192 + 64 + k];
    _Float16 h = (_Float16)v;
    W[i] = h;
    W[512 * 128 + i] = (_Float16)(v - (float)h);
  }
}

// f32 [N,K] row-major -> 16-col frag-ordered split-f16
__global__ void refrag_f32(const float* __restrict__ W, _Float16* __restrict__ F,
                           int N, int Kc) {
  int idx = blockIdx.x * 256 + threadIdx.x;
  int total = (N >> 4) * Kc * 64;
  if (idx >= total) return;
  int l = idx & 63;
  int c = (idx >> 6) % Kc;
  int T = (idx >> 6) / Kc;
  int n = T * 16 + (l & 15);
  int k = c * 32 + (l >> 4) * 8;
  int K = Kc * 32;
  const float* src = W + (size_t)n * K + k;
  _Float16* dst = F + ((size_t)((T * Kc + c) * 2) * 64 + l) * 8;
  for (int e = 0; e < 8; e++) {
    float v = src[e];
    _Float16 h = (_Float16)v;
    dst[e] = h;
    dst[512 + e] = (_Float16)(v - (float)h);
  }
}

// split-plane [N,K] -> 16-col frag-ordered
__global__ void refrag_planes(const _Float16* __restrict__ Ws, size_t plane,
                              _Float16* __restrict__ F, int N, int Kc) {
  int idx = blockIdx.x * 256 + threadIdx.x;
  int total = (N >> 4) * Kc * 64;
  if (idx >= total) return;
  int l = idx & 63;
  int c = (idx >> 6) % Kc;
  int T = (idx >> 6) / Kc;
  int n = T * 16 + (l & 15);
  int k = c * 32 + (l >> 4) * 8;
  int K = Kc * 32;
  const _Float16* src = Ws + (size_t)n * K + k;
  _Float16* dst = F + ((size_t)((T * Kc + c) * 2) * 64 + l) * 8;
  for (int e = 0; e < 8; e++) {
    dst[e] = src[e];
    dst[512 + e] = src[plane + e];
  }
}

__global__ void build_misc(const float* __restrict__ Wp1, const float* __restrict__ Wp_emb,
                           const float* __restrict__ bp_emb, const float* __restrict__ bp1,
                           const float* __restrict__ b_ih, const float* __restrict__ b_hh,
                           float* __restrict__ Uc, float* __restrict__ c1,
                           float* __restrict__ bias_gi) {
  int r = blockIdx.x * 256 + threadIdx.x;
  if (r < 512) {
    float u0 = 0.f, u1 = 0.f, cc = 0.f;
    for (int e = 0; e < 64; e++) {
      float w = Wp1[r * 192 + e];
      u0 += w * Wp_emb[e * 2 + 0];
      u1 += w * Wp_emb[e * 2 + 1];
      cc += w * bp_emb[e];
    }
    Uc[r * 2 + 0] = u0;
    Uc[r * 2 + 1] = u1;
    c1[r] = bp1[r] + cc;
    int u = r >> 2, gate = r & 3;
    bias_gi[r] = b_ih[gate * 128 + u] + b_hh[gate * 128 + u];
  }
}

__global__ void init_state(const float* __restrict__ lp, const float* __restrict__ lpr,
                           const float* __restrict__ h0, const float* __restrict__ c0,
                           const float* __restrict__ W_emb, const float* __restrict__ b_emb,
                           _Float16* __restrict__ A_lstm, size_t PL_AL,
                           float* __restrict__ c_state, float* __restrict__ curr_pos) {
  int row = blockIdx.x;
  int t = threadIdx.x;  // 192
  float v;
  if (t < 64) {
    v = lpr[row * 2] * W_emb[t * 2] + lpr[row * 2 + 1] * W_emb[t * 2 + 1] + b_emb[t];
  } else {
    int u = t - 64;
    v = h0[(size_t)row * 128 + u];
    c_state[(size_t)row * 128 + u] = c0[(size_t)row * 128 + u];
  }
  _Float16 h = (_Float16)v;
  A_lstm[(size_t)row * 192 + t] = h;
  A_lstm[PL_AL + (size_t)row * 192 + t] = (_Float16)(v - (float)h);
  if (t < 2) curr_pos[row * 2 + t] = lp[row * 2 + t];
}

// ---------------- generic split-fp16 GEMM (proven): LDS A + frag-B ----------

template <int K, int RELU>
__global__ __launch_bounds__(256) void gemm_f16f(
    const _Float16* __restrict__ A, size_t aPl, int lda,
    const _Float16* __restrict__ Bf,
    const float* __restrict__ bias,
    float* __restrict__ outF, int ldoF,
    _Float16* __restrict__ outS, size_t oPl, int ldoS) {
  constexpr int Kc = K / 32;
  __shared__ _Float16 Ah[64][40], Al[64][40];
  const int tid = threadIdx.x;
  const int lane = tid & 63;
  const int wid = tid >> 6;
  const int wm = wid & 1, wn = wid >> 1;
  const int m0 = blockIdx.x * 64, n0 = blockIdx.y * 64;

  f32x4 acc[2][2];
#pragma unroll
  for (int a = 0; a < 2; a++)
#pragma unroll
    for (int b = 0; b < 2; b++) acc[a][b] = (f32x4){0.f, 0.f, 0.f, 0.f};

  const int srow = tid >> 2, sc = (tid & 3) * 8;
  const int ar = wm * 32 + (lane & 15);
  const int kk = (lane >> 4) * 8;
  const int T0 = (n0 >> 4) + wn * 2;

  for (int c = 0; c < Kc; c++) {
    const int k0 = c * 32;
    const _Float16* ap = A + (size_t)(m0 + srow) * lda + k0 + sc;
    uint4 avh = *(const uint4*)ap;
    uint4 avl = *(const uint4*)(ap + aPl);
    const _Float16* fb0 = Bf + ((size_t)((T0 * Kc + c) * 2) * 64 + lane) * 8;
    const _Float16* fb1 = Bf + ((size_t)(((T0 + 1) * Kc + c) * 2) * 64 + lane) * 8;
    f16x8 bh0 = *(const f16x8*)fb0, bl0 = *(const f16x8*)(fb0 + 512);
    f16x8 bh1 = *(const f16x8*)fb1, bl1 = *(const f16x8*)(fb1 + 512);
    *(uint4*)&Ah[srow][sc] = avh;
    *(uint4*)&Al[srow][sc] = avl;
    __syncthreads();
    f16x8 ah0 = *(const f16x8*)&Ah[ar][kk];
    f16x8 ah1 = *(const f16x8*)&Ah[ar + 16][kk];
    f16x8 al0 = *(const f16x8*)&Al[ar][kk];
    f16x8 al1 = *(const f16x8*)&Al[ar + 16][kk];
    acc[0][0] = MFMA16(ah0, bh0, acc[0][0]);
    acc[0][0] = MFMA16(ah0, bl0, acc[0][0]);
    acc[0][0] = MFMA16(al0, bh0, acc[0][0]);
    acc[0][1] = MFMA16(ah0, bh1, acc[0][1]);
    acc[0][1] = MFMA16(ah0, bl1, acc[0][1]);
    acc[0][1] = MFMA16(al0, bh1, acc[0][1]);
    acc[1][0] = MFMA16(ah1, bh0, acc[1][0]);
    acc[1][0] = MFMA16(ah1, bl0, acc[1][0]);
    acc[1][0] = MFMA16(al1, bh0, acc[1][0]);
    acc[1][1] = MFMA16(ah1, bh1, acc[1][1]);
    acc[1][1] = MFMA16(ah1, bl1, acc[1][1]);
    acc[1][1] = MFMA16(al1, bh1, acc[1][1]);
    __syncthreads();
  }
#pragma unroll
  for (int mi = 0; mi < 2; mi++)
#pragma unroll
    for (int ni = 0; ni < 2; ni++)
#pragma unroll
      for (int r = 0; r < 4; r++) {
        int row = m0 + wm * 32 + mi * 16 + (lane >> 4) * 4 + r;
        int col = n0 + wn * 32 + ni * 16 + (lane & 15);
        float v = acc[mi][ni][r];
        if (bias) v += bias[col];
        if (RELU) v = fmaxf(v, 0.f);
        if (outF) outF[(size_t)row * ldoF + col] = v;
        if (outS) {
          _Float16 h = (_Float16)v;
          outS[(size_t)row * ldoS + col] = h;
          outS[oPl + (size_t)row * ldoS + col] = (_Float16)(v - (float)h);
        }
      }
}

// ---------------- fused gates GEMM + LSTM pointwise ----------------

__global__ __launch_bounds__(256) void gates_lstm(
    const _Float16* __restrict__ A, size_t aPl,
    const _Float16* __restrict__ Bf,
    const float* __restrict__ bias,
    float* __restrict__ c_state,
    _Float16* __restrict__ A_mlp, size_t oPl) {
  constexpr int Kc = 6;
  __shared__ _Float16 Ah[64][40], Al[64][40];
  __shared__ float sacc[64][68];
  const int tid = threadIdx.x;
  const int lane = tid & 63;
  const int wid = tid >> 6;
  const int wm = wid & 1, wn = wid >> 1;
  const int m0 = blockIdx.x * 64, n0 = blockIdx.y * 64;

  f32x4 acc[2][2];
#pragma unroll
  for (int a = 0; a < 2; a++)
#pragma unroll
    for (int b = 0; b < 2; b++) acc[a][b] = (f32x4){0.f, 0.f, 0.f, 0.f};

  const int srow = tid >> 2, sc = (tid & 3) * 8;
  const int ar = wm * 32 + (lane & 15);
  const int kk = (lane >> 4) * 8;
  const int T0 = (n0 >> 4) + wn * 2;

  for (int c = 0; c < Kc; c++) {
    const int k0 = c * 32;
    const _Float16* ap = A + (size_t)(m0 + srow) * 192 + k0 + sc;
    uint4 avh = *(const uint4*)ap;
    uint4 avl = *(const uint4*)(ap + aPl);
    const _Float16* fb0 = Bf + ((size_t)((T0 * Kc + c) * 2) * 64 + lane) * 8;
    const _Float16* fb1 = Bf + ((size_t)(((T0 + 1) * Kc + c) * 2) * 64 + lane) * 8;
    f16x8 bh0 = *(const f16x8*)fb0, bl0 = *(const f16x8*)(fb0 + 512);
    f16x8 bh1 = *(const f16x8*)fb1, bl1 = *(const f16x8*)(fb1 + 512);
    *(uint4*)&Ah[srow][sc] = avh;
    *(uint4*)&Al[srow][sc] = avl;
    __syncthreads();
    f16x8 ah0 = *(const f16x8*)&Ah[ar][kk];
    f16x8 ah1 = *(const f16x8*)&Ah[ar + 16][kk];
    f16x8 al0 = *(const f16x8*)&Al[ar][kk];
    f16x8 al1 = *(const f16x8*)&Al[ar + 16][kk];
    acc[0][0] = MFMA16(ah0, bh0, acc[0][0]);
    acc[0][0] = MFMA16(ah0, bl0, acc[0][0]);
    acc[0][0] = MFMA16(al0, bh0, acc[0][0]);
    acc[0][1] = MFMA16(ah0, bh1, acc[0][1]);
    acc[0][1] = MFMA16(ah0, bl1, acc[0][1]);
    acc[0][1] = MFMA16(al0, bh1, acc[0][1]);
    acc[1][0] = MFMA16(ah1, bh0, acc[1][0]);
    acc[1][0] = MFMA16(ah1, bl0, acc[1][0]);
    acc[1][0] = MFMA16(al1, bh0, acc[1][0]);
    acc[1][1] = MFMA16(ah1, bh1, acc[1][1]);
    acc[1][1] = MFMA16(ah1, bl1, acc[1][1]);
    acc[1][1] = MFMA16(al1, bh1, acc[1][1]);
    __syncthreads();
  }
#pragma unroll
  for (int mi = 0; mi < 2; mi++)
#pragma unroll
    for (int ni = 0; ni < 2; ni++)
#pragma unroll
      for (int r = 0; r < 4; r++) {
        int row_l = wm * 32 + mi * 16 + (lane >> 4) * 4 + r;
        int col_l = wn * 32 + ni * 16 + (lane & 15);
        sacc[row_l][col_l] = acc[mi][ni][r] + bias[n0 + col_l];
      }
  __syncthreads();
  const int n0u = n0 >> 2;
#pragma unroll
  for (int q = 0; q < 4; q++) {
    int cell = q * 256 + tid;
    int r_l = cell >> 4, u_l = cell & 15;
    float gi = sacc[r_l][u_l * 4 + 0];
    float gf = sacc[r_l][u_l * 4 + 1];
    float gg = sacc[r_l][u_l * 4 + 2];
    float go = sacc[r_l][u_l * 4 + 3];
    int row = m0 + r_l, u = n0u + u_l;
    float si = 1.f / (1.f + expf(-gi));
    float sf = 1.f / (1.f + expf(-gf));
    float so = 1.f / (1.f + expf(-go));
    float cst = sf * c_state[(size_t)row * 128 + u] + si * tanhf(gg);
    c_state[(size_t)row * 128 + u] = cst;
    float h = so * tanhf(cst);
    _Float16 hh = (_Float16)h;
    A_mlp[(size_t)row * 1152 + u] = hh;
    A_mlp[oPl + (size_t)row * 1152 + u] = (_Float16)(h - (float)hh);
  }
}

// ---------------- hpart GEMM + fused pose head / dec_in (by==0) ----------------

__global__ __launch_bounds__(256) void hpart_pose(
    const _Float16* __restrict__ A, size_t aPl,
    const _Float16* __restrict__ Bf,
    const float* __restrict__ c1,
    float* __restrict__ hpart,
    const float* __restrict__ W_pos, const float* __restrict__ b_pos,
    const float* __restrict__ W_emb, const float* __restrict__ b_emb,
    float* __restrict__ rels_out, float* __restrict__ curr_pos,
    _Float16* __restrict__ A_lstm, size_t alPl) {
  constexpr int Kc = 4;
  __shared__ _Float16 Ah[64][40], Al[64][40];
  __shared__ float srel[64][2];
  const int tid = threadIdx.x;
  const int lane = tid & 63;
  const int wid = tid >> 6;
  const int wm = wid & 1, wn = wid >> 1;
  const int m0 = blockIdx.x * 64, n0 = blockIdx.y * 64;
  const int by0 = (blockIdx.y == 0);

  f32x4 acc[2][2];
#pragma unroll
  for (int a = 0; a < 2; a++)
#pragma unroll
    for (int b = 0; b < 2; b++) acc[a][b] = (f32x4){0.f, 0.f, 0.f, 0.f};

  const int srow = tid >> 2, sc = (tid & 3) * 8;
  const int ar = wm * 32 + (lane & 15);
  const int kk = (lane >> 4) * 8;
  const int T0 = (n0 >> 4) + wn * 2;
  float pp0 = 0.f, pp1 = 0.f;

  for (int c = 0; c < Kc; c++) {
    const int k0 = c * 32;
    const _Float16* ap = A + (size_t)(m0 + srow) * 1152 + k0 + sc;
    uint4 avh = *(const uint4*)ap;
    uint4 avl = *(const uint4*)(ap + aPl);
    if (by0) {
      union { uint4 u; _Float16 f[8]; } uh, ul;
      uh.u = avh; ul.u = avl;
#pragma unroll
      for (int e = 0; e < 8; e++) {
        float hv = (float)uh.f[e] + (float)ul.f[e];
        int k = k0 + sc + e;
        pp0 += hv * W_pos[k];
        pp1 += hv * W_pos[128 + k];
      }
    }
    const _Float16* fb0 = Bf + ((size_t)((T0 * Kc + c) * 2) * 64 + lane) * 8;
    const _Float16* fb1 = Bf + ((size_t)(((T0 + 1) * Kc + c) * 2) * 64 + lane) * 8;
    f16x8 bh0 = *(const f16x8*)fb0, bl0 = *(const f16x8*)(fb0 + 512);
    f16x8 bh1 = *(const f16x8*)fb1, bl1 = *(const f16x8*)(fb1 + 512);
    *(uint4*)&Ah[srow][sc] = avh;
    *(uint4*)&Al[srow][sc] = avl;
    __syncthreads();
    f16x8 ah0 = *(const f16x8*)&Ah[ar][kk];
    f16x8 ah1 = *(const f16x8*)&Ah[ar + 16][kk];
    f16x8 al0 = *(const f16x8*)&Al[ar][kk];
    f16x8 al1 = *(const f16x8*)&Al[ar + 16][kk];
    acc[0][0] = MFMA16(ah0, bh0, acc[0][0]);
    acc[0][0] = MFMA16(ah0, bl0, acc[0][0]);
    acc[0][0] = MFMA16(al0, bh0, acc[0][0]);
    acc[0][1] = MFMA16(ah0, bh1, acc[0][1]);
    acc[0][1] = MFMA16(ah0, bl1, acc[0][1]);
    acc[0][1] = MFMA16(al0, bh1, acc[0][1]);
    acc[1][0] = MFMA16(ah1, bh0, acc[1][0]);
    acc[1][0] = MFMA16(ah1, bl0, acc[1][0]);
    acc[1][0] = MFMA16(al1, bh0, acc[1][0]);
    acc[1][1] = MFMA16(ah1, bh1, acc[1][1]);
    acc[1][1] = MFMA16(ah1, bl1, acc[1][1]);
    acc[1][1] = MFMA16(al1, bh1, acc[1][1]);
    __syncthreads();
  }
#pragma unroll
  for (int mi = 0; mi < 2; mi++)
#pragma unroll
    for (int ni = 0; ni < 2; ni++)
#pragma unroll
      for (int r = 0; r < 4; r++) {
        int row = m0 + wm * 32 + mi * 16 + (lane >> 4) * 4 + r;
        int col = n0 + wn * 32 + ni * 16 + (lane & 15);
        hpart[(size_t)row * 512 + col] = acc[mi][ni][r] + c1[col];
      }
  if (by0) {
    pp0 += __shfl_xor(pp0, 1);
    pp0 += __shfl_xor(pp0, 2);
    pp1 += __shfl_xor(pp1, 1);
    pp1 += __shfl_xor(pp1, 2);
    if ((tid & 3) == 0) {
      int row = m0 + srow;
      float r0 = pp0 + b_pos[0], r1 = pp1 + b_pos[1];
      rels_out[(size_t)row * 2 + 0] = r0;
      rels_out[(size_t)row * 2 + 1] = r1;
      curr_pos[(size_t)row * 2 + 0] += r0;
      curr_pos[(size_t)row * 2 + 1] += r1;
      srel[srow][0] = r0;
      srel[srow][1] = r1;
    }
    __syncthreads();
#pragma unroll
    for (int q = 0; q < 16; q++) {
      int idx = q * 256 + tid;
      int r_l = idx >> 6, cc = idx & 63;
      int row = m0 + r_l;
      float v = srel[r_l][0] * W_emb[cc * 2] + srel[r_l][1] * W_emb[cc * 2 + 1] + b_emb[cc];
      _Float16 hh = (_Float16)v;
      A_lstm[(size_t)row * 192 + cc] = hh;
      A_lstm[alPl + (size_t)row * 192 + cc] = (_Float16)(v - (float)hh);
    }
  }
}

// ---------------- fused pool (R4/R11 structure, 2-term split: Ah*Bh + Ah*Bl) ----
// grid: 64 g x 6 it x 4 nt = 1536 blocks; tile 96 rows x 256 cols, K=512 (16 steps).
// A-lo dropped (rel err ~2.4e-4): no Al buffer, build emits hi only, 24 MFMA/iter.

__global__ __launch_bounds__(512) void pool_gemm(
    const float* __restrict__ hpart,
    const float* __restrict__ curr_pos,
    const float* __restrict__ Uc,
    const _Float16* __restrict__ W2f,    // 16-col frag-ordered hi/lo (Kc=16)
    const float* __restrict__ bp2,
    _Float16* __restrict__ A_mlp, size_t oPl) {
  __shared__ _Float16 Ah[96][40];
  __shared__ float Us0[96], Us1[96];
  __shared__ int pool_tile[4][256];
  int b = blockIdx.x;
  int nt = b & 3;
  int it = (b >> 2) % 6;
  int g = b / 24;
  int tid = threadIdx.x;
  int lane = tid & 63, wid = tid >> 6;
  int wm = wid & 1, wn = wid >> 1;  // wm:2, wn:4

  int* pt = &pool_tile[0][0];
  pt[tid] = 0;
  pt[tid + 512] = 0;

  if (tid < 96) {
    int r = tid;
    int i = it * 4 + r / 24;
    int j = r % 24;
    float pix = curr_pos[(g * 24 + i) * 2 + 0];
    float piy = curr_pos[(g * 24 + i) * 2 + 1];
    float dx = curr_pos[(g * 24 + j) * 2 + 0] - pix;
    float dy = curr_pos[(g * 24 + j) * 2 + 1] - piy;
    float nrm = sqrtf(dx * dx + dy * dy);
    float inv = 1.f / fmaxf(nrm, 1e-12f);
    Us0[r] = dx * inv;
    Us1[r] = dy * inv;
  }

  f32x4 acc[3][4];
#pragma unroll
  for (int a = 0; a < 3; a++)
#pragma unroll
    for (int c = 0; c < 4; c++) acc[a][c] = (f32x4){0.f, 0.f, 0.f, 0.f};

  const int kc = (2 * tid) & 31;
  const int rb = tid >> 4;

  for (int c16 = 0; c16 < 16; c16++) {
    const int k0 = c16 * 32;
    // B fragment loads (global, frag-ordered, coalesced 1KB/wave)
    f16x8 bh[4], bl[4];
#pragma unroll
    for (int ni = 0; ni < 4; ni++) {
      int T = nt * 16 + wn * 4 + ni;
      const _Float16* fb = W2f + ((size_t)((T * 16 + c16) * 2) * 64 + lane) * 8;
      bh[ni] = *(const f16x8*)fb;
      bl[ni] = *(const f16x8*)(fb + 512);
    }
    __syncthreads();  // A buffer free (prev reads done); Us ready on first iter
    // build A slice [96][32] hi only
#pragma unroll
    for (int s = 0; s < 3; s++) {
      int r = s * 32 + rb;
      int j = r % 24;
      float2 hp = *(const float2*)(hpart + ((size_t)(g * 24 + j)) * 512 + k0 + kc);
      float4 uc = *(const float4*)(Uc + (size_t)(k0 + kc) * 2);
      float u0 = Us0[r], u1 = Us1[r];
      float v0 = fmaxf(hp.x + u0 * uc.x + u1 * uc.y, 0.f);
      float v1 = fmaxf(hp.y + u0 * uc.z + u1 * uc.w, 0.f);
      *(unsigned int*)&Ah[r][kc] =
          (unsigned int)h2u((_Float16)v0) | ((unsigned int)h2u((_Float16)v1) << 16);
    }
    __syncthreads();
    const int kk = (lane >> 4) * 8;
    f16x8 ah[3];
#pragma unroll
    for (int mi = 0; mi < 3; mi++) {
      int ar = wm * 48 + mi * 16 + (lane & 15);
      ah[mi] = *(const f16x8*)&Ah[ar][kk];
    }
#pragma unroll
    for (int mi = 0; mi < 3; mi++)
#pragma unroll
      for (int ni = 0; ni < 4; ni++) {
        acc[mi][ni] = MFMA16(ah[mi], bh[ni], acc[mi][ni]);
        acc[mi][ni] = MFMA16(ah[mi], bl[ni], acc[mi][ni]);
      }
  }
  __syncthreads();
#pragma unroll
  for (int mi = 0; mi < 3; mi++)
#pragma unroll
    for (int ni = 0; ni < 4; ni++)
#pragma unroll
      for (int r = 0; r < 4; r++) {
        int rl = wm * 48 + mi * 16 + (lane >> 4) * 4 + r;  // 0..95
        int il = rl / 24;                                  // 0..3
        int nl = wn * 64 + ni * 16 + (lane & 15);          // 0..255
        float z = fmaxf(acc[mi][ni][r] + bp2[nt * 256 + nl], 0.f);
        atomicMax(&pool_tile[il][nl], __float_as_int(z));
      }
  __syncthreads();
  for (int idx = tid; idx < 1024; idx += 512) {
    int il = idx >> 8, nl = idx & 255;
    int row = g * 24 + it * 4 + il;
    float z = __int_as_float(pool_tile[il][nl]);
    _Float16 h = (_Float16)z;
    A_mlp[(size_t)row * 1152 + 128 + nt * 256 + nl] = h;
    A_mlp[oPl + (size_t)row * 1152 + 128 + nt * 256 + nl] = (_Float16)(z - (float)h);
  }
}

// ---------------- host ----------------

extern "C" void kernel_launch(void* const* d_in, const int* in_sizes, int n_in,
                              void* d_out, int out_size, void* d_ws, size_t ws_size,
                              hipStream_t stream) {
  (void)in_sizes; (void)n_in; (void)out_size; (void)ws_size;
  const float* last_pos     = (const float*)d_in[0];
  const float* last_pos_rel = (const float*)d_in[1];
  const float* h0    = (const float*)d_in[2];
  const float* c0    = (const float*)d_in[3];
  const float* W_emb = (const float*)d_in[5];
  const float* b_emb = (const float*)d_in[6];
  const float* W_ih  = (const float*)d_in[7];
  const float* W_hh  = (const float*)d_in[8];
  const float* b_ih  = (const float*)d_in[9];
  const float* b_hh  = (const float*)d_in[10];
  const float* W_pos = (const float*)d_in[11];
  const float* b_pos = (const float*)d_in[12];
  const float* Wp_emb = (const float*)d_in[13];
  const float* bp_emb = (const float*)d_in[14];
  const float* Wp1 = (const float*)d_in[15];
  const float* bp1 = (const float*)d_in[16];
  const float* Wp2 = (const float*)d_in[17];
  const float* bp2 = (const float*)d_in[18];
  const float* Wm1 = (const float*)d_in[19];
  const float* bm1 = (const float*)d_in[20];
  const float* Wm2 = (const float*)d_in[21];
  const float* bm2 = (const float*)d_in[22];

  const size_t PL_AL = (size_t)1536 * 192;
  const size_t PL_AM = (size_t)1536 * 1152;
  const size_t PL_DH = (size_t)1536 * 1024;

  char* ws = (char*)d_ws;
  size_t off = 0;
  auto alloc = [&](size_t bytes) -> void* {
    void* p = ws + off;
    off = (off + bytes + 255) & ~(size_t)255;
    return p;
  };
  _Float16* Wgi_s  = (_Float16*)alloc((size_t)512 * 192 * 2 * 2);
  _Float16* Wp1b_s = (_Float16*)alloc((size_t)512 * 128 * 2 * 2);
  _Float16* Wgi_f  = (_Float16*)alloc((size_t)32 * 6 * 1024 * 2);
  _Float16* Wp1b_f = (_Float16*)alloc((size_t)32 * 4 * 1024 * 2);
  _Float16* W2f    = (_Float16*)alloc((size_t)64 * 16 * 1024 * 2);
  _Float16* Wm1_f  = (_Float16*)alloc((size_t)64 * 36 * 1024 * 2);
  _Float16* Wm2_f  = (_Float16*)alloc((size_t)8 * 32 * 1024 * 2);
  float* Uc      = (float*)alloc(512 * 2 * 4);
  float* c1      = (float*)alloc(512 * 4);
  float* bias_gi = (float*)alloc(512 * 4);
  _Float16* A_lstm = (_Float16*)alloc(PL_AL * 2 * 2);
  float* c_state = (float*)alloc((size_t)1536 * 128 * 4);
  _Float16* A_mlp = (_Float16*)alloc(PL_AM * 2 * 2);
  float* curr_pos = (float*)alloc(1536 * 2 * 4);
  float* hpart = (float*)alloc((size_t)1536 * 512 * 4);
  _Float16* dh = (_Float16*)alloc(PL_DH * 2 * 2);

  float* rels = (float*)d_out;                      // [12,1536,2]
  float* h_out = ((float*)d_out) + 12 * 1536 * 2;   // [1536,128]

  // ---- init weights + state ----
  build_wg<<<(98304 + 255) / 256, 256, 0, stream>>>(W_ih, W_hh, Wgi_s);
  build_wp1b<<<(65536 + 255) / 256, 256, 0, stream>>>(Wp1, Wp1b_s);
  refrag_planes<<<(12288 + 255) / 256, 256, 0, stream>>>(Wgi_s, 98304, Wgi_f, 512, 6);
  refrag_planes<<<(8192 + 255) / 256, 256, 0, stream>>>(Wp1b_s, 65536, Wp1b_f, 512, 4);
  refrag_f32<<<(65536 + 255) / 256, 256, 0, stream>>>(Wp2, W2f, 1024, 16);
  refrag_f32<<<(147456 + 255) / 256, 256, 0, stream>>>(Wm1, Wm1_f, 1024, 36);
  refrag_f32<<<(16384 + 255) / 256, 256, 0, stream>>>(Wm2, Wm2_f, 128, 32);
  build_misc<<<2, 256, 0, stream>>>(Wp1, Wp_emb, bp_emb, bp1, b_ih, b_hh, Uc, c1, bias_gi);
  init_state<<<1536, 192, 0, stream>>>(last_pos, last_pos_rel, h0, c0, W_emb, b_emb,
                                       A_lstm, PL_AL, c_state, curr_pos);

  for (int t = 0; t < 12; t++) {
    gates_lstm<<<dim3(24, 8), 256, 0, stream>>>(A_lstm, PL_AL, Wgi_f, bias_gi,
                                                c_state, A_mlp, PL_AM);
    hpart_pose<<<dim3(24, 8), 256, 0, stream>>>(A_mlp, PL_AM, Wp1b_f, c1, hpart,
                                                W_pos, b_pos, W_emb, b_emb,
                                                rels + (size_t)t * 1536 * 2, curr_pos,
                                                A_lstm, PL_AL);
    pool_gemm<<<1536, 512, 0, stream>>>(hpart, curr_pos, Uc, W2f, bp2, A_mlp, PL_AM);
    gemm_f16f<1152, 1><<<dim3(24, 16), 256, 0, stream>>>(
        A_mlp, PL_AM, 1152, Wm1_f, bm1, (float*)nullptr, 0, dh, PL_DH, 1024);
    float* houtF = (t == 11) ? h_out : (float*)nullptr;
    gemm_f16f<1024, 1><<<dim3(24, 2), 256, 0, stream>>>(
        dh, PL_DH, 1024, Wm2_f, bm2, houtF, 128, A_lstm + 64, PL_AL, 192);
  }
}

// Round 14
// 1722.845 us; speedup vs baseline: 1.2068x; 1.0481x over previous
//
#include <hip/hip_runtime.h>
#include <hip/hip_bf16.h>

typedef __attribute__((ext_vector_type(4))) float f32x4;
typedef __attribute__((ext_vector_type(8))) _Float16 f16x8;

static __device__ __forceinline__ unsigned short h2u(_Float16 h) {
  union { _Float16 h; unsigned short u; } v; v.h = h; return v.u;
}

#define MFMA16(a, b, c) __builtin_amdgcn_mfma_f32_16x16x32_f16(a, b, c, 0, 0, 0)

// ---------------- init kernels ----------------

// gate-interleaved Wg: out row n' = u*4+gate <- [W_ih|W_hh] row gate*128+u
__global__ void build_wg(const float* __restrict__ W_ih, const float* __restrict__ W_hh,
                         _Float16* __restrict__ Wg) {
  int i = blockIdx.x * 256 + threadIdx.x;
  if (i < 512 * 192) {
    int rp = i / 192, k = i % 192;
    int u = rp >> 2, gate = rp & 3;
    int sr = gate * 128 + u;
    float v = (k < 64) ? W_ih[sr * 64 + k] : W_hh[sr * 128 + (k - 64)];
    _Float16 h = (_Float16)v;
    Wg[i] = h;
    Wg[512 * 192 + i] = (_Float16)(v - (float)h);
  }
}

__global__ void build_wp1b(const float* __restrict__ Wp1, _Float16* __restrict__ W) {
  int i = blockIdx.x * 256 + threadIdx.x;
  if (i < 512 * 128) {
    int r = i >> 7, k = i & 127;
    float v = Wp1[r * 192 + 64 + k];
    _Float16 h = (_Float16)v;
    W[i] = h;
    W[512 * 128 + i] = (_Float16)(v - (float)h);
  }
}

// f32 [N,K] row-major -> 16-col frag-ordered split-f16
__global__ void refrag_f32(const float* __restrict__ W, _Float16* __restrict__ F,
                           int N, int Kc) {
  int idx = blockIdx.x * 256 + threadIdx.x;
  int total = (N >> 4) * Kc * 64;
  if (idx >= total) return;
  int l = idx & 63;
  int c = (idx >> 6) % Kc;
  int T = (idx >> 6) / Kc;
  int n = T * 16 + (l & 15);
  int k = c * 32 + (l >> 4) * 8;
  int K = Kc * 32;
  const float* src = W + (size_t)n * K + k;
  _Float16* dst = F + ((size_t)((T * Kc + c) * 2) * 64 + l) * 8;
  for (int e = 0; e < 8; e++) {
    float v = src[e];
    _Float16 h = (_Float16)v;
    dst[e] = h;
    dst[512 + e] = (_Float16)(v - (float)h);
  }
}

// split-plane [N,K] -> 16-col frag-ordered
__global__ void refrag_planes(const _Float16* __restrict__ Ws, size_t plane,
                              _Float16* __restrict__ F, int N, int Kc) {
  int idx = blockIdx.x * 256 + threadIdx.x;
  int total = (N >> 4) * Kc * 64;
  if (idx >= total) return;
  int l = idx & 63;
  int c = (idx >> 6) % Kc;
  int T = (idx >> 6) / Kc;
  int n = T * 16 + (l & 15);
  int k = c * 32 + (l >> 4) * 8;
  int K = Kc * 32;
  const _Float16* src = Ws + (size_t)n * K + k;
  _Float16* dst = F + ((size_t)((T * Kc + c) * 2) * 64 + l) * 8;
  for (int e = 0; e < 8; e++) {
    dst[e] = src[e];
    dst[512 + e] = src[plane + e];
  }
}

__global__ void build_misc(const float* __restrict__ Wp1, const float* __restrict__ Wp_emb,
                           const float* __restrict__ bp_emb, const float* __restrict__ bp1,
                           const float* __restrict__ b_ih, const float* __restrict__ b_hh,
                           float* __restrict__ Uc, float* __restrict__ c1,
                           float* __restrict__ bias_gi) {
  int r = blockIdx.x * 256 + threadIdx.x;
  if (r < 512) {
    float u0 = 0.f, u1 = 0.f, cc = 0.f;
    for (int e = 0; e < 64; e++) {
      float w = Wp1[r * 192 + e];
      u0 += w * Wp_emb[e * 2 + 0];
      u1 += w * Wp_emb[e * 2 + 1];
      cc += w * bp_emb[e];
    }
    Uc[r * 2 + 0] = u0;
    Uc[r * 2 + 1] = u1;
    c1[r] = bp1[r] + cc;
    int u = r >> 2, gate = r & 3;
    bias_gi[r] = b_ih[gate * 128 + u] + b_hh[gate * 128 + u];
  }
}

__global__ void init_state(const float* __restrict__ lp, const float* __restrict__ lpr,
                           const float* __restrict__ h0, const float* __restrict__ c0,
                           const float* __restrict__ W_emb, const float* __restrict__ b_emb,
                           _Float16* __restrict__ A_lstm, size_t PL_AL,
                           float* __restrict__ c_state, float* __restrict__ curr_pos) {
  int row = blockIdx.x;
  int t = threadIdx.x;  // 192
  float v;
  if (t < 64) {
    v = lpr[row * 2] * W_emb[t * 2] + lpr[row * 2 + 1] * W_emb[t * 2 + 1] + b_emb[t];
  } else {
    int u = t - 64;
    v = h0[(size_t)row * 128 + u];
    c_state[(size_t)row * 128 + u] = c0[(size_t)row * 128 + u];
  }
  _Float16 h = (_Float16)v;
  A_lstm[(size_t)row * 192 + t] = h;
  A_lstm[PL_AL + (size_t)row * 192 + t] = (_Float16)(v - (float)h);
  if (t < 2) curr_pos[row * 2 + t] = lp[row * 2 + t];
}

// ---------------- generic split-fp16 GEMM (proven): LDS A + frag-B ----------

template <int K, int RELU>
__global__ __launch_bounds__(256) void gemm_f16f(
    const _Float16* __restrict__ A, size_t aPl, int lda,
    const _Float16* __restrict__ Bf,
    const float* __restrict__ bias,
    float* __restrict__ outF, int ldoF,
    _Float16* __restrict__ outS, size_t oPl, int ldoS) {
  constexpr int Kc = K / 32;
  __shared__ _Float16 Ah[64][40], Al[64][40];
  const int tid = threadIdx.x;
  const int lane = tid & 63;
  const int wid = tid >> 6;
  const int wm = wid & 1, wn = wid >> 1;
  const int m0 = blockIdx.x * 64, n0 = blockIdx.y * 64;

  f32x4 acc[2][2];
#pragma unroll
  for (int a = 0; a < 2; a++)
#pragma unroll
    for (int b = 0; b < 2; b++) acc[a][b] = (f32x4){0.f, 0.f, 0.f, 0.f};

  const int srow = tid >> 2, sc = (tid & 3) * 8;
  const int ar = wm * 32 + (lane & 15);
  const int kk = (lane >> 4) * 8;
  const int T0 = (n0 >> 4) + wn * 2;

  for (int c = 0; c < Kc; c++) {
    const int k0 = c * 32;
    const _Float16* ap = A + (size_t)(m0 + srow) * lda + k0 + sc;
    uint4 avh = *(const uint4*)ap;
    uint4 avl = *(const uint4*)(ap + aPl);
    const _Float16* fb0 = Bf + ((size_t)((T0 * Kc + c) * 2) * 64 + lane) * 8;
    const _Float16* fb1 = Bf + ((size_t)(((T0 + 1) * Kc + c) * 2) * 64 + lane) * 8;
    f16x8 bh0 = *(const f16x8*)fb0, bl0 = *(const f16x8*)(fb0 + 512);
    f16x8 bh1 = *(const f16x8*)fb1, bl1 = *(const f16x8*)(fb1 + 512);
    *(uint4*)&Ah[srow][sc] = avh;
    *(uint4*)&Al[srow][sc] = avl;
    __syncthreads();
    f16x8 ah0 = *(const f16x8*)&Ah[ar][kk];
    f16x8 ah1 = *(const f16x8*)&Ah[ar + 16][kk];
    f16x8 al0 = *(const f16x8*)&Al[ar][kk];
    f16x8 al1 = *(const f16x8*)&Al[ar + 16][kk];
    acc[0][0] = MFMA16(ah0, bh0, acc[0][0]);
    acc[0][0] = MFMA16(ah0, bl0, acc[0][0]);
    acc[0][0] = MFMA16(al0, bh0, acc[0][0]);
    acc[0][1] = MFMA16(ah0, bh1, acc[0][1]);
    acc[0][1] = MFMA16(ah0, bl1, acc[0][1]);
    acc[0][1] = MFMA16(al0, bh1, acc[0][1]);
    acc[1][0] = MFMA16(ah1, bh0, acc[1][0]);
    acc[1][0] = MFMA16(ah1, bl0, acc[1][0]);
    acc[1][0] = MFMA16(al1, bh0, acc[1][0]);
    acc[1][1] = MFMA16(ah1, bh1, acc[1][1]);
    acc[1][1] = MFMA16(ah1, bl1, acc[1][1]);
    acc[1][1] = MFMA16(al1, bh1, acc[1][1]);
    __syncthreads();
  }
#pragma unroll
  for (int mi = 0; mi < 2; mi++)
#pragma unroll
    for (int ni = 0; ni < 2; ni++)
#pragma unroll
      for (int r = 0; r < 4; r++) {
        int row = m0 + wm * 32 + mi * 16 + (lane >> 4) * 4 + r;
        int col = n0 + wn * 32 + ni * 16 + (lane & 15);
        float v = acc[mi][ni][r];
        if (bias) v += bias[col];
        if (RELU) v = fmaxf(v, 0.f);
        if (outF) outF[(size_t)row * ldoF + col] = v;
        if (outS) {
          _Float16 h = (_Float16)v;
          outS[(size_t)row * ldoS + col] = h;
          outS[oPl + (size_t)row * ldoS + col] = (_Float16)(v - (float)h);
        }
      }
}

// ---------------- fused gates GEMM + LSTM pointwise ----------------

__global__ __launch_bounds__(256) void gates_lstm(
    const _Float16* __restrict__ A, size_t aPl,
    const _Float16* __restrict__ Bf,
    const float* __restrict__ bias,
    float* __restrict__ c_state,
    _Float16* __restrict__ A_mlp, size_t oPl) {
  constexpr int Kc = 6;
  __shared__ _Float16 Ah[64][40], Al[64][40];
  __shared__ float sacc[64][68];
  const int tid = threadIdx.x;
  const int lane = tid & 63;
  const int wid = tid >> 6;
  const int wm = wid & 1, wn = wid >> 1;
  const int m0 = blockIdx.x * 64, n0 = blockIdx.y * 64;

  f32x4 acc[2][2];
#pragma unroll
  for (int a = 0; a < 2; a++)
#pragma unroll
    for (int b = 0; b < 2; b++) acc[a][b] = (f32x4){0.f, 0.f, 0.f, 0.f};

  const int srow = tid >> 2, sc = (tid & 3) * 8;
  const int ar = wm * 32 + (lane & 15);
  const int kk = (lane >> 4) * 8;
  const int T0 = (n0 >> 4) + wn * 2;

  for (int c = 0; c < Kc; c++) {
    const int k0 = c * 32;
    const _Float16* ap = A + (size_t)(m0 + srow) * 192 + k0 + sc;
    uint4 avh = *(const uint4*)ap;
    uint4 avl = *(const uint4*)(ap + aPl);
    const _Float16* fb0 = Bf + ((size_t)((T0 * Kc + c) * 2) * 64 + lane) * 8;
    const _Float16* fb1 = Bf + ((size_t)(((T0 + 1) * Kc + c) * 2) * 64 + lane) * 8;
    f16x8 bh0 = *(const f16x8*)fb0, bl0 = *(const f16x8*)(fb0 + 512);
    f16x8 bh1 = *(const f16x8*)fb1, bl1 = *(const f16x8*)(fb1 + 512);
    *(uint4*)&Ah[srow][sc] = avh;
    *(uint4*)&Al[srow][sc] = avl;
    __syncthreads();
    f16x8 ah0 = *(const f16x8*)&Ah[ar][kk];
    f16x8 ah1 = *(const f16x8*)&Ah[ar + 16][kk];
    f16x8 al0 = *(const f16x8*)&Al[ar][kk];
    f16x8 al1 = *(const f16x8*)&Al[ar + 16][kk];
    acc[0][0] = MFMA16(ah0, bh0, acc[0][0]);
    acc[0][0] = MFMA16(ah0, bl0, acc[0][0]);
    acc[0][0] = MFMA16(al0, bh0, acc[0][0]);
    acc[0][1] = MFMA16(ah0, bh1, acc[0][1]);
    acc[0][1] = MFMA16(ah0, bl1, acc[0][1]);
    acc[0][1] = MFMA16(al0, bh1, acc[0][1]);
    acc[1][0] = MFMA16(ah1, bh0, acc[1][0]);
    acc[1][0] = MFMA16(ah1, bl0, acc[1][0]);
    acc[1][0] = MFMA16(al1, bh0, acc[1][0]);
    acc[1][1] = MFMA16(ah1, bh1, acc[1][1]);
    acc[1][1] = MFMA16(ah1, bl1, acc[1][1]);
    acc[1][1] = MFMA16(al1, bh1, acc[1][1]);
    __syncthreads();
  }
#pragma unroll
  for (int mi = 0; mi < 2; mi++)
#pragma unroll
    for (int ni = 0; ni < 2; ni++)
#pragma unroll
      for (int r = 0; r < 4; r++) {
        int row_l = wm * 32 + mi * 16 + (lane >> 4) * 4 + r;
        int col_l = wn * 32 + ni * 16 + (lane & 15);
        sacc[row_l][col_l] = acc[mi][ni][r] + bias[n0 + col_l];
      }
  __syncthreads();
  const int n0u = n0 >> 2;
#pragma unroll
  for (int q = 0; q < 4; q++) {
    int cell = q * 256 + tid;
    int r_l = cell >> 4, u_l = cell & 15;
    float gi = sacc[r_l][u_l * 4 + 0];
    float gf = sacc[r_l][u_l * 4 + 1];
    float gg = sacc[r_l][u_l * 4 + 2];
    float go = sacc[r_l][u_l * 4 + 3];
    int row = m0 + r_l, u = n0u + u_l;
    float si = 1.f / (1.f + expf(-gi));
    float sf = 1.f / (1.f + expf(-gf));
    float so = 1.f / (1.f + expf(-go));
    float cst = sf * c_state[(size_t)row * 128 + u] + si * tanhf(gg);
    c_state[(size_t)row * 128 + u] = cst;
    float h = so * tanhf(cst);
    _Float16 hh = (_Float16)h;
    A_mlp[(size_t)row * 1152 + u] = hh;
    A_mlp[oPl + (size_t)row * 1152 + u] = (_Float16)(h - (float)hh);
  }
}

// ---------------- hpart GEMM + fused pose head / dec_in (by==0) ----------------

__global__ __launch_bounds__(256) void hpart_pose(
    const _Float16* __restrict__ A, size_t aPl,
    const _Float16* __restrict__ Bf,
    const float* __restrict__ c1,
    float* __restrict__ hpart,
    const float* __restrict__ W_pos, const float* __restrict__ b_pos,
    const float* __restrict__ W_emb, const float* __restrict__ b_emb,
    float* __restrict__ rels_out, float* __restrict__ curr_pos,
    _Float16* __restrict__ A_lstm, size_t alPl) {
  constexpr int Kc = 4;
  __shared__ _Float16 Ah[64][40], Al[64][40];
  __shared__ float srel[64][2];
  const int tid = threadIdx.x;
  const int lane = tid & 63;
  const int wid = tid >> 6;
  const int wm = wid & 1, wn = wid >> 1;
  const int m0 = blockIdx.x * 64, n0 = blockIdx.y * 64;
  const int by0 = (blockIdx.y == 0);

  f32x4 acc[2][2];
#pragma unroll
  for (int a = 0; a < 2; a++)
#pragma unroll
    for (int b = 0; b < 2; b++) acc[a][b] = (f32x4){0.f, 0.f, 0.f, 0.f};

  const int srow = tid >> 2, sc = (tid & 3) * 8;
  const int ar = wm * 32 + (lane & 15);
  const int kk = (lane >> 4) * 8;
  const int T0 = (n0 >> 4) + wn * 2;
  float pp0 = 0.f, pp1 = 0.f;

  for (int c = 0; c < Kc; c++) {
    const int k0 = c * 32;
    const _Float16* ap = A + (size_t)(m0 + srow) * 1152 + k0 + sc;
    uint4 avh = *(const uint4*)ap;
    uint4 avl = *(const uint4*)(ap + aPl);
    if (by0) {
      union { uint4 u; _Float16 f[8]; } uh, ul;
      uh.u = avh; ul.u = avl;
#pragma unroll
      for (int e = 0; e < 8; e++) {
        float hv = (float)uh.f[e] + (float)ul.f[e];
        int k = k0 + sc + e;
        pp0 += hv * W_pos[k];
        pp1 += hv * W_pos[128 + k];
      }
    }
    const _Float16* fb0 = Bf + ((size_t)((T0 * Kc + c) * 2) * 64 + lane) * 8;
    const _Float16* fb1 = Bf + ((size_t)(((T0 + 1) * Kc + c) * 2) * 64 + lane) * 8;
    f16x8 bh0 = *(const f16x8*)fb0, bl0 = *(const f16x8*)(fb0 + 512);
    f16x8 bh1 = *(const f16x8*)fb1, bl1 = *(const f16x8*)(fb1 + 512);
    *(uint4*)&Ah[srow][sc] = avh;
    *(uint4*)&Al[srow][sc] = avl;
    __syncthreads();
    f16x8 ah0 = *(const f16x8*)&Ah[ar][kk];
    f16x8 ah1 = *(const f16x8*)&Ah[ar + 16][kk];
    f16x8 al0 = *(const f16x8*)&Al[ar][kk];
    f16x8 al1 = *(const f16x8*)&Al[ar + 16][kk];
    acc[0][0] = MFMA16(ah0, bh0, acc[0][0]);
    acc[0][0] = MFMA16(ah0, bl0, acc[0][0]);
    acc[0][0] = MFMA16(al0, bh0, acc[0][0]);
    acc[0][1] = MFMA16(ah0, bh1, acc[0][1]);
    acc[0][1] = MFMA16(ah0, bl1, acc[0][1]);
    acc[0][1] = MFMA16(al0, bh1, acc[0][1]);
    acc[1][0] = MFMA16(ah1, bh0, acc[1][0]);
    acc[1][0] = MFMA16(ah1, bl0, acc[1][0]);
    acc[1][0] = MFMA16(al1, bh0, acc[1][0]);
    acc[1][1] = MFMA16(ah1, bh1, acc[1][1]);
    acc[1][1] = MFMA16(ah1, bl1, acc[1][1]);
    acc[1][1] = MFMA16(al1, bh1, acc[1][1]);
    __syncthreads();
  }
#pragma unroll
  for (int mi = 0; mi < 2; mi++)
#pragma unroll
    for (int ni = 0; ni < 2; ni++)
#pragma unroll
      for (int r = 0; r < 4; r++) {
        int row = m0 + wm * 32 + mi * 16 + (lane >> 4) * 4 + r;
        int col = n0 + wn * 32 + ni * 16 + (lane & 15);
        hpart[(size_t)row * 512 + col] = acc[mi][ni][r] + c1[col];
      }
  if (by0) {
    pp0 += __shfl_xor(pp0, 1);
    pp0 += __shfl_xor(pp0, 2);
    pp1 += __shfl_xor(pp1, 1);
    pp1 += __shfl_xor(pp1, 2);
    if ((tid & 3) == 0) {
      int row = m0 + srow;
      float r0 = pp0 + b_pos[0], r1 = pp1 + b_pos[1];
      rels_out[(size_t)row * 2 + 0] = r0;
      rels_out[(size_t)row * 2 + 1] = r1;
      curr_pos[(size_t)row * 2 + 0] += r0;
      curr_pos[(size_t)row * 2 + 1] += r1;
      srel[srow][0] = r0;
      srel[srow][1] = r1;
    }
    __syncthreads();
#pragma unroll
    for (int q = 0; q < 16; q++) {
      int idx = q * 256 + tid;
      int r_l = idx >> 6, cc = idx & 63;
      int row = m0 + r_l;
      float v = srel[r_l][0] * W_emb[cc * 2] + srel[r_l][1] * W_emb[cc * 2 + 1] + b_emb[cc];
      _Float16 hh = (_Float16)v;
      A_lstm[(size_t)row * 192 + cc] = hh;
      A_lstm[alPl + (size_t)row * 192 + cc] = (_Float16)(v - (float)hh);
    }
  }
}

// ---------------- fused pool (R13 2-term + hoisted A-source loads) ----------
// grid: 64 g x 6 it x 4 nt = 1536 blocks; tile 96 rows x 256 cols, K=512 (16 steps).
// hp/uc loads for iter c issued WITH the B loads (before barrier 1) so both
// latency windows overlap in one vmcnt drain; build between barriers is pure VALU+LDS.

__global__ __launch_bounds__(512) void pool_gemm(
    const float* __restrict__ hpart,
    const float* __restrict__ curr_pos,
    const float* __restrict__ Uc,
    const _Float16* __restrict__ W2f,    // 16-col frag-ordered hi/lo (Kc=16)
    const float* __restrict__ bp2,
    _Float16* __restrict__ A_mlp, size_t oPl) {
  __shared__ _Float16 Ah[96][40];
  __shared__ float Us0[96], Us1[96];
  __shared__ int pool_tile[4][256];
  int b = blockIdx.x;
  int nt = b & 3;
  int it = (b >> 2) % 6;
  int g = b / 24;
  int tid = threadIdx.x;
  int lane = tid & 63, wid = tid >> 6;
  int wm = wid & 1, wn = wid >> 1;  // wm:2, wn:4

  int* pt = &pool_tile[0][0];
  pt[tid] = 0;
  pt[tid + 512] = 0;

  if (tid < 96) {
    int r = tid;
    int i = it * 4 + r / 24;
    int j = r % 24;
    float pix = curr_pos[(g * 24 + i) * 2 + 0];
    float piy = curr_pos[(g * 24 + i) * 2 + 1];
    float dx = curr_pos[(g * 24 + j) * 2 + 0] - pix;
    float dy = curr_pos[(g * 24 + j) * 2 + 1] - piy;
    float nrm = sqrtf(dx * dx + dy * dy);
    float inv = 1.f / fmaxf(nrm, 1e-12f);
    Us0[r] = dx * inv;
    Us1[r] = dy * inv;
  }

  f32x4 acc[3][4];
#pragma unroll
  for (int a = 0; a < 3; a++)
#pragma unroll
    for (int c = 0; c < 4; c++) acc[a][c] = (f32x4){0.f, 0.f, 0.f, 0.f};

  const int kc = (2 * tid) & 31;
  const int rb = tid >> 4;
  const int j0 = rb % 24, j1 = (rb + 32) % 24, j2 = (rb + 64) % 24;
  const float* hp0 = hpart + ((size_t)(g * 24 + j0)) * 512 + kc;
  const float* hp1 = hpart + ((size_t)(g * 24 + j1)) * 512 + kc;
  const float* hp2 = hpart + ((size_t)(g * 24 + j2)) * 512 + kc;

  for (int c16 = 0; c16 < 16; c16++) {
    const int k0 = c16 * 32;
    // B fragment loads + A-source loads for THIS iter (all before barrier 1;
    // latencies overlap in one drain)
    f16x8 bh[4], bl[4];
#pragma unroll
    for (int ni = 0; ni < 4; ni++) {
      int T = nt * 16 + wn * 4 + ni;
      const _Float16* fb = W2f + ((size_t)((T * 16 + c16) * 2) * 64 + lane) * 8;
      bh[ni] = *(const f16x8*)fb;
      bl[ni] = *(const f16x8*)(fb + 512);
    }
    float2 q0 = *(const float2*)(hp0 + k0);
    float2 q1 = *(const float2*)(hp1 + k0);
    float2 q2 = *(const float2*)(hp2 + k0);
    float4 uc = *(const float4*)(Uc + (size_t)(k0 + kc) * 2);
    __syncthreads();  // A buffer free (prev frag reads done); Us ready on first iter
    // build A slice [96][32] hi-only — pure VALU + LDS writes
    {
      float u0 = Us0[rb], u1 = Us1[rb];
      float v0 = fmaxf(q0.x + u0 * uc.x + u1 * uc.y, 0.f);
      float v1 = fmaxf(q0.y + u0 * uc.z + u1 * uc.w, 0.f);
      *(unsigned int*)&Ah[rb][kc] =
          (unsigned int)h2u((_Float16)v0) | ((unsigned int)h2u((_Float16)v1) << 16);
      u0 = Us0[rb + 32]; u1 = Us1[rb + 32];
      v0 = fmaxf(q1.x + u0 * uc.x + u1 * uc.y, 0.f);
      v1 = fmaxf(q1.y + u0 * uc.z + u1 * uc.w, 0.f);
      *(unsigned int*)&Ah[rb + 32][kc] =
          (unsigned int)h2u((_Float16)v0) | ((unsigned int)h2u((_Float16)v1) << 16);
      u0 = Us0[rb + 64]; u1 = Us1[rb + 64];
      v0 = fmaxf(q2.x + u0 * uc.x + u1 * uc.y, 0.f);
      v1 = fmaxf(q2.y + u0 * uc.z + u1 * uc.w, 0.f);
      *(unsigned int*)&Ah[rb + 64][kc] =
          (unsigned int)h2u((_Float16)v0) | ((unsigned int)h2u((_Float16)v1) << 16);
    }
    __syncthreads();
    const int kk = (lane >> 4) * 8;
    f16x8 ah[3];
#pragma unroll
    for (int mi = 0; mi < 3; mi++) {
      int ar = wm * 48 + mi * 16 + (lane & 15);
      ah[mi] = *(const f16x8*)&Ah[ar][kk];
    }
#pragma unroll
    for (int mi = 0; mi < 3; mi++)
#pragma unroll
      for (int ni = 0; ni < 4; ni++) {
        acc[mi][ni] = MFMA16(ah[mi], bh[ni], acc[mi][ni]);
        acc[mi][ni] = MFMA16(ah[mi], bl[ni], acc[mi][ni]);
      }
  }
  __syncthreads();
#pragma unroll
  for (int mi = 0; mi < 3; mi++)
#pragma unroll
    for (int ni = 0; ni < 4; ni++)
#pragma unroll
      for (int r = 0; r < 4; r++) {
        int rl = wm * 48 + mi * 16 + (lane >> 4) * 4 + r;  // 0..95
        int il = rl / 24;                                  // 0..3
        int nl = wn * 64 + ni * 16 + (lane & 15);          // 0..255
        float z = fmaxf(acc[mi][ni][r] + bp2[nt * 256 + nl], 0.f);
        atomicMax(&pool_tile[il][nl], __float_as_int(z));
      }
  __syncthreads();
  for (int idx = tid; idx < 1024; idx += 512) {
    int il = idx >> 8, nl = idx & 255;
    int row = g * 24 + it * 4 + il;
    float z = __int_as_float(pool_tile[il][nl]);
    _Float16 h = (_Float16)z;
    A_mlp[(size_t)row * 1152 + 128 + nt * 256 + nl] = h;
    A_mlp[oPl + (size_t)row * 1152 + 128 + nt * 256 + nl] = (_Float16)(z - (float)h);
  }
}

// ---------------- host ----------------

extern "C" void kernel_launch(void* const* d_in, const int* in_sizes, int n_in,
                              void* d_out, int out_size, void* d_ws, size_t ws_size,
                              hipStream_t stream) {
  (void)in_sizes; (void)n_in; (void)out_size; (void)ws_size;
  const float* last_pos     = (const float*)d_in[0];
  const float* last_pos_rel = (const float*)d_in[1];
  const float* h0    = (const float*)d_in[2];
  const float* c0    = (const float*)d_in[3];
  const float* W_emb = (const float*)d_in[5];
  const float* b_emb = (const float*)d_in[6];
  const float* W_ih  = (const float*)d_in[7];
  const float* W_hh  = (const float*)d_in[8];
  const float* b_ih  = (const float*)d_in[9];
  const float* b_hh  = (const float*)d_in[10];
  const float* W_pos = (const float*)d_in[11];
  const float* b_pos = (const float*)d_in[12];
  const float* Wp_emb = (const float*)d_in[13];
  const float* bp_emb = (const float*)d_in[14];
  const float* Wp1 = (const float*)d_in[15];
  const float* bp1 = (const float*)d_in[16];
  const float* Wp2 = (const float*)d_in[17];
  const float* bp2 = (const float*)d_in[18];
  const float* Wm1 = (const float*)d_in[19];
  const float* bm1 = (const float*)d_in[20];
  const float* Wm2 = (const float*)d_in[21];
  const float* bm2 = (const float*)d_in[22];

  const size_t PL_AL = (size_t)1536 * 192;
  const size_t PL_AM = (size_t)1536 * 1152;
  const size_t PL_DH = (size_t)1536 * 1024;

  char* ws = (char*)d_ws;
  size_t off = 0;
  auto alloc = [&](size_t bytes) -> void* {
    void* p = ws + off;
    off = (off + bytes + 255) & ~(size_t)255;
    return p;
  };
  _Float16* Wgi_s  = (_Float16*)alloc((size_t)512 * 192 * 2 * 2);
  _Float16* Wp1b_s = (_Float16*)alloc((size_t)512 * 128 * 2 * 2);
  _Float16* Wgi_f  = (_Float16*)alloc((size_t)32 * 6 * 1024 * 2);
  _Float16* Wp1b_f = (_Float16*)alloc((size_t)32 * 4 * 1024 * 2);
  _Float16* W2f    = (_Float16*)alloc((size_t)64 * 16 * 1024 * 2);
  _Float16* Wm1_f  = (_Float16*)alloc((size_t)64 * 36 * 1024 * 2);
  _Float16* Wm2_f  = (_Float16*)alloc((size_t)8 * 32 * 1024 * 2);
  float* Uc      = (float*)alloc(512 * 2 * 4);
  float* c1      = (float*)alloc(512 * 4);
  float* bias_gi = (float*)alloc(512 * 4);
  _Float16* A_lstm = (_Float16*)alloc(PL_AL * 2 * 2);
  float* c_state = (float*)alloc((size_t)1536 * 128 * 4);
  _Float16* A_mlp = (_Float16*)alloc(PL_AM * 2 * 2);
  float* curr_pos = (float*)alloc(1536 * 2 * 4);
  float* hpart = (float*)alloc((size_t)1536 * 512 * 4);
  _Float16* dh = (_Float16*)alloc(PL_DH * 2 * 2);

  float* rels = (float*)d_out;                      // [12,1536,2]
  float* h_out = ((float*)d_out) + 12 * 1536 * 2;   // [1536,128]

  // ---- init weights + state ----
  build_wg<<<(98304 + 255) / 256, 256, 0, stream>>>(W_ih, W_hh, Wgi_s);
  build_wp1b<<<(65536 + 255) / 256, 256, 0, stream>>>(Wp1, Wp1b_s);
  refrag_planes<<<(12288 + 255) / 256, 256, 0, stream>>>(Wgi_s, 98304, Wgi_f, 512, 6);
  refrag_planes<<<(8192 + 255) / 256, 256, 0, stream>>>(Wp1b_s, 65536, Wp1b_f, 512, 4);
  refrag_f32<<<(65536 + 255) / 256, 256, 0, stream>>>(Wp2, W2f, 1024, 16);
  refrag_f32<<<(147456 + 255) / 256, 256, 0, stream>>>(Wm1, Wm1_f, 1024, 36);
  refrag_f32<<<(16384 + 255) / 256, 256, 0, stream>>>(Wm2, Wm2_f, 128, 32);
  build_misc<<<2, 256, 0, stream>>>(Wp1, Wp_emb, bp_emb, bp1, b_ih, b_hh, Uc, c1, bias_gi);
  init_state<<<1536, 192, 0, stream>>>(last_pos, last_pos_rel, h0, c0, W_emb, b_emb,
                                       A_lstm, PL_AL, c_state, curr_pos);

  for (int t = 0; t < 12; t++) {
    gates_lstm<<<dim3(24, 8), 256, 0, stream>>>(A_lstm, PL_AL, Wgi_f, bias_gi,
                                                c_state, A_mlp, PL_AM);
    hpart_pose<<<dim3(24, 8), 256, 0, stream>>>(A_mlp, PL_AM, Wp1b_f, c1, hpart,
                                                W_pos, b_pos, W_emb, b_emb,
                                                rels + (size_t)t * 1536 * 2, curr_pos,
                                                A_lstm, PL_AL);
    pool_gemm<<<1536, 512, 0, stream>>>(hpart, curr_pos, Uc, W2f, bp2, A_mlp, PL_AM);
    gemm_f16f<1152, 1><<<dim3(24, 16), 256, 0, stream>>>(
        A_mlp, PL_AM, 1152, Wm1_f, bm1, (float*)nullptr, 0, dh, PL_DH, 1024);
    float* houtF = (t == 11) ? h_out : (float*)nullptr;
    gemm_f16f<1024, 1><<<dim3(24, 2), 256, 0, stream>>>(
        dh, PL_DH, 1024, Wm2_f, bm2, houtF, 128, A_lstm + 64, PL_AL, 192);
  }
}